// Round 1
// baseline (238.010 us; speedup 1.0000x reference)
//
#include <hip/hip_runtime.h>
#include <hip/hip_bf16.h>

// DenseConv2d: input (32,128,56,56) f32, weight (256,128,3,3) f32, bias (256) f32
// stride 1, pad 1 -> out (32,256,56,56) f32.
// Implicit GEMM: C[256][100352] = W[256][1152] x im2col[1152][100352], bf16 MFMA.

typedef __attribute__((ext_vector_type(8))) short bf16x8;
typedef __attribute__((ext_vector_type(8))) unsigned short ushort8;
typedef __attribute__((ext_vector_type(4))) float f32x4;

#define HW      56
#define SPATIAL 3136        // 56*56
#define C_IN    128
#define K_OUT   256
#define N_IMG   32
#define GEMM_K  1152        // 9 * 128, ordered k = tap*128 + c
#define GEMM_N  100352      // 32 * 3136

#define BM 128
#define BN 128
#define BK 32
#define LDK 40              // padded row stride in halves (80 B -> 2-way-free banks)

__device__ __forceinline__ unsigned short f2bf(float f) {
    union { float f; unsigned int u; } v; v.f = f;
    unsigned int u = v.u + 0x7FFFu + ((v.u >> 16) & 1u);   // RTNE
    return (unsigned short)(u >> 16);
}

// weight [256][128][3][3] f32  ->  w2 [256][9][128] bf16  (k_out, tap, c)
__global__ void wtrans_kernel(const float* __restrict__ w, unsigned short* __restrict__ w2) {
    int idx = blockIdx.x * 256 + threadIdx.x;       // 294912 total
    int ko  = idx / GEMM_K;
    int r   = idx % GEMM_K;
    int tap = r >> 7;                               // r / 128
    int c   = r & 127;
    w2[idx] = f2bf(w[(ko * C_IN + c) * 9 + tap]);
}

template<bool USE_W2>
__global__ __launch_bounds__(256)
void conv_mfma_kernel(const float* __restrict__ in,
                      const float* __restrict__ wraw,
                      const unsigned short* __restrict__ w2,
                      const float* __restrict__ bias,
                      float* __restrict__ out) {
    __shared__ __attribute__((aligned(16))) unsigned short lA[BM * LDK];
    __shared__ __attribute__((aligned(16))) unsigned short lB[BN * LDK];

    const int tid = threadIdx.x;
    const int m0  = blockIdx.y * BM;     // output-channel tile
    const int g0  = blockIdx.x * BN;     // spatial tile

    const int wave = tid >> 6;
    const int lane = tid & 63;
    const int wr = wave >> 1, wc = wave & 1;   // 2x2 waves -> 64x64 each
    const int la  = lane & 15;
    const int lkh = lane >> 4;                 // 0..3
    const int lk  = lkh * 8;                   // k base within BK=32

    f32x4 acc[4][4];
    #pragma unroll
    for (int i = 0; i < 4; ++i)
        #pragma unroll
        for (int j = 0; j < 4; ++j)
            acc[i][j] = (f32x4){0.f, 0.f, 0.f, 0.f};

    // ---- B staging coords (fixed per thread) ----
    const int jj = tid & 127;            // column within tile
    const int kb = (tid >> 7) * 16;      // kk base: 0 or 16
    const int g    = g0 + jj;
    const int nimg = g / SPATIAL;
    const int pos  = g % SPATIAL;
    const int oh   = pos / HW;
    const int ow   = pos % HW;

    for (int tap = 0; tap < 9; ++tap) {
        const int dr = tap / 3 - 1;
        const int ds = tap % 3 - 1;
        const int ih = oh + dr;
        const int iw = ow + ds;
        const bool valid = ((unsigned)ih < HW) && ((unsigned)iw < HW);
        const float* src = in + ((nimg * C_IN) * HW + ih) * HW + iw;  // + c*SPATIAL

        for (int c0 = 0; c0 < C_IN; c0 += BK) {
            // ---- stage A: 128x32 bf16 weights ----
            #pragma unroll
            for (int i = 0; i < 2; ++i) {
                const int ch  = tid * 2 + i;     // 512 chunks of 8
                const int row = ch >> 2;
                const int kp  = (ch & 3) * 8;
                if (USE_W2) {
                    const ushort8 v = *reinterpret_cast<const ushort8*>(
                        w2 + (m0 + row) * GEMM_K + tap * C_IN + c0 + kp);
                    *reinterpret_cast<ushort8*>(&lA[row * LDK + kp]) = v;
                } else {
                    ushort8 v;
                    #pragma unroll
                    for (int e = 0; e < 8; ++e)
                        v[e] = f2bf(wraw[((m0 + row) * C_IN + c0 + kp + e) * 9 + tap]);
                    *reinterpret_cast<ushort8*>(&lA[row * LDK + kp]) = v;
                }
            }
            // ---- stage B: 128 cols x 32 k, im2col gather (coalesced in w) ----
            {
                ushort8 v0, v1;
                #pragma unroll
                for (int i = 0; i < 8; ++i) {
                    const float f = valid ? src[(c0 + kb + i) * SPATIAL] : 0.f;
                    v0[i] = f2bf(f);
                }
                #pragma unroll
                for (int i = 0; i < 8; ++i) {
                    const float f = valid ? src[(c0 + kb + 8 + i) * SPATIAL] : 0.f;
                    v1[i] = f2bf(f);
                }
                *reinterpret_cast<ushort8*>(&lB[jj * LDK + kb])     = v0;
                *reinterpret_cast<ushort8*>(&lB[jj * LDK + kb + 8]) = v1;
            }
            __syncthreads();

            bf16x8 af[4], bv[4];
            #pragma unroll
            for (int f = 0; f < 4; ++f) {
                af[f] = *reinterpret_cast<const bf16x8*>(&lA[(wr * 64 + f * 16 + la) * LDK + lk]);
                bv[f] = *reinterpret_cast<const bf16x8*>(&lB[(wc * 64 + f * 16 + la) * LDK + lk]);
            }
            #pragma unroll
            for (int fi = 0; fi < 4; ++fi)
                #pragma unroll
                for (int fj = 0; fj < 4; ++fj)
                    acc[fi][fj] = __builtin_amdgcn_mfma_f32_16x16x32_bf16(
                        af[fi], bv[fj], acc[fi][fj], 0, 0, 0);
            __syncthreads();
        }
    }

    // ---- epilogue: D col = lane&15, row = (lane>>4)*4 + reg (verified m89/m91) ----
    const int mbase = m0 + wr * 64;
    const int cbase = g0 + wc * 64;
    #pragma unroll
    for (int fi = 0; fi < 4; ++fi) {
        float bvv[4];
        #pragma unroll
        for (int r = 0; r < 4; ++r)
            bvv[r] = bias[mbase + fi * 16 + lkh * 4 + r];
        #pragma unroll
        for (int fj = 0; fj < 4; ++fj) {
            const int gcol = cbase + fj * 16 + la;
            const int n2 = gcol / SPATIAL;
            const int p2 = gcol % SPATIAL;
            float* op = out + (size_t)(n2 * K_OUT) * SPATIAL + p2;
            #pragma unroll
            for (int r = 0; r < 4; ++r) {
                const int m = mbase + fi * 16 + lkh * 4 + r;
                op[(size_t)m * SPATIAL] = acc[fi][fj][r] + bvv[r];
            }
        }
    }
}

extern "C" void kernel_launch(void* const* d_in, const int* in_sizes, int n_in,
                              void* d_out, int out_size, void* d_ws, size_t ws_size,
                              hipStream_t stream) {
    const float* in   = (const float*)d_in[0];
    const float* w    = (const float*)d_in[1];
    const float* bias = (const float*)d_in[2];
    float* out = (float*)d_out;

    const size_t w2_bytes = (size_t)K_OUT * GEMM_K * sizeof(unsigned short); // 589824
    dim3 grid(GEMM_N / BN, K_OUT / BM);   // (784, 2)

    if (ws_size >= w2_bytes) {
        unsigned short* w2 = (unsigned short*)d_ws;
        wtrans_kernel<<<(K_OUT * GEMM_K) / 256, 256, 0, stream>>>(w, w2);
        conv_mfma_kernel<true><<<grid, 256, 0, stream>>>(in, w, w2, bias, out);
    } else {
        conv_mfma_kernel<false><<<grid, 256, 0, stream>>>(in, w, nullptr, bias, out);
    }
}

// Round 2
// 133.303 us; speedup vs baseline: 1.7855x; 1.7855x over previous
//
#include <hip/hip_runtime.h>
#include <hip/hip_bf16.h>
#include <stdint.h>

// DenseConv2d: input (32,128,56,56) f32, weight (256,128,3,3) f32, bias (256) f32
// stride 1, pad 1 -> out (32,256,56,56) f32.
// Implicit GEMM: C[256][100352] = W[256][1152] x im2col[1152][100352], bf16 MFMA.
// Round 2: bf16 NHWC pre-pass + m97-style global_load_lds staging, BK=64.

typedef __attribute__((ext_vector_type(8))) short bf16x8;
typedef __attribute__((ext_vector_type(8))) unsigned short ushort8;
typedef __attribute__((ext_vector_type(4))) float f32x4;

#define HW      56
#define SPATIAL 3136        // 56*56
#define C_IN    128
#define K_OUT   256
#define GEMM_K  1152        // 9 * 128, ordered k = tap*128 + c
#define GEMM_N  100352      // 32 * 3136

#define BM 128
#define BN 128
#define BK 64
#define NSTAGE 18           // 9 taps * (128/64)

__device__ __forceinline__ unsigned short f2bf(float f) {
    union { float f; unsigned int u; } v; v.f = f;
    unsigned int u = v.u + 0x7FFFu + ((v.u >> 16) & 1u);   // RTNE
    return (unsigned short)(u >> 16);
}

__device__ __forceinline__ void gload16(const unsigned short* g, unsigned short* l) {
    __builtin_amdgcn_global_load_lds(
        (const __attribute__((address_space(1))) unsigned int*)(g),
        (__attribute__((address_space(3))) unsigned int*)(l),
        16, 0, 0);
}

// weight [256][128][3][3] f32 -> w2 [256][9][128] bf16  (k_out, tap, c)
__global__ void wtrans_kernel(const float* __restrict__ w, unsigned short* __restrict__ w2) {
    int idx = blockIdx.x * 256 + threadIdx.x;       // 294912 total
    int ko  = idx / GEMM_K;
    int r   = idx % GEMM_K;
    int tap = r >> 7;
    int c   = r & 127;
    w2[idx] = f2bf(w[(ko * C_IN + c) * 9 + tap]);
}

// input [32][128][56][56] f32 -> nhwc [32][56][56][128] bf16
__global__ __launch_bounds__(256)
void intrans_kernel(const float* __restrict__ in, unsigned short* __restrict__ nhwc) {
    __shared__ __attribute__((aligned(16))) unsigned short l[56 * 136];
    const int bx = blockIdx.x;                      // 32*56 = 1792
    const int n = bx / HW, h = bx % HW;
    const int tid = threadIdx.x;
    const float* src = in + (size_t)n * C_IN * SPATIAL + h * HW;   // + c*SPATIAL + w
    #pragma unroll
    for (int i = 0; i < 28; ++i) {                  // 7168 = 28*256
        int idx = i * 256 + tid;
        int c = idx / HW, w = idx % HW;
        l[w * 136 + c] = f2bf(src[(size_t)c * SPATIAL + w]);
    }
    __syncthreads();
    unsigned short* dst = nhwc + ((size_t)(n * HW + h) * HW) * C_IN;
    #pragma unroll
    for (int j = 0; j < 4; ++j) {
        int chunk = j * 256 + tid;                  // 896 = 56*16 chunks of 8
        if (chunk < 896) {
            int w = chunk >> 4, c8 = chunk & 15;
            *reinterpret_cast<ushort8*>(dst + w * C_IN + c8 * 8) =
                *reinterpret_cast<const ushort8*>(&l[w * 136 + c8 * 8]);
        }
    }
}

// ---------------- main kernel: m97-style, global_load_lds, linear LDS ----------------
__global__ __launch_bounds__(256)
void conv_mfma_nhwc(const unsigned short* __restrict__ nhwc,
                    const unsigned short* __restrict__ w2,
                    const unsigned short* __restrict__ zbuf,
                    const float* __restrict__ bias,
                    float* __restrict__ out) {
    __shared__ __attribute__((aligned(16))) unsigned short lA[BM * BK];
    __shared__ __attribute__((aligned(16))) unsigned short lB[BN * BK];

    const int tid  = threadIdx.x;
    const int m0   = blockIdx.y * BM;
    const int g0   = blockIdx.x * BN;
    const int wave = tid >> 6;
    const int lane = tid & 63;
    const int wr = wave >> 1, wc = wave & 1;
    const int la = lane & 15, lkh = lane >> 4;
    const int lr = lane >> 3;            // sub-row within a gload call (0..7)
    const int lg = (lane & 7) * 8;       // granule offset in halves

    f32x4 acc[4][4];
    #pragma unroll
    for (int i = 0; i < 4; ++i)
        #pragma unroll
        for (int j = 0; j < 4; ++j)
            acc[i][j] = (f32x4){0.f, 0.f, 0.f, 0.f};

    // per-lane B column precompute (column fixed per (lane, j))
    int ohs[4], ows[4];
    long long pbase[4];
    #pragma unroll
    for (int j = 0; j < 4; ++j) {
        int col  = wave * 32 + j * 8 + lr;
        int g    = g0 + col;
        int nimg = g / SPATIAL;
        int pos  = g - nimg * SPATIAL;
        int oh   = pos / HW;
        int ow   = pos - oh * HW;
        ohs[j] = oh; ows[j] = ow;
        pbase[j] = ((long long)(nimg * HW + oh) * HW + ow) * C_IN;
    }
    const unsigned short* wbase = w2 + (size_t)m0 * GEMM_K + lr * GEMM_K + lg;

    for (int s = 0; s < NSTAGE; ++s) {
        const int tap = s >> 1, ci = (s & 1) * 64;
        const int dr = tap / 3 - 1, ds = tap % 3 - 1;

        // stage A: 128 rows x 64 ch bf16, 4 gload calls per wave
        #pragma unroll
        for (int j = 0; j < 4; ++j) {
            const int rbase = j * 32 + wave * 8;
            gload16(wbase + (size_t)rbase * GEMM_K + tap * C_IN + ci,
                    &lA[rbase * BK]);
        }
        // stage B: 128 cols x 64 ch bf16, boundary cols redirect to zero page
        #pragma unroll
        for (int j = 0; j < 4; ++j) {
            const int ih = ohs[j] + dr, iw = ows[j] + ds;
            const bool valid = ((unsigned)ih < HW) && ((unsigned)iw < HW);
            const unsigned short* gsrc = valid
                ? nhwc + pbase[j] + (dr * HW + ds) * C_IN + ci + lg
                : zbuf + lg;
            gload16(gsrc, &lB[(wave * 32 + j * 8) * BK]);
        }
        __syncthreads();   // drains vmcnt before barrier (compiler-inserted)

        #pragma unroll
        for (int ks = 0; ks < 2; ++ks) {
            bf16x8 af[4], bv[4];
            #pragma unroll
            for (int f = 0; f < 4; ++f) {
                af[f] = *reinterpret_cast<const bf16x8*>(&lA[(wr * 64 + f * 16 + la) * BK + ks * 32 + lkh * 8]);
                bv[f] = *reinterpret_cast<const bf16x8*>(&lB[(wc * 64 + f * 16 + la) * BK + ks * 32 + lkh * 8]);
            }
            #pragma unroll
            for (int fi = 0; fi < 4; ++fi)
                #pragma unroll
                for (int fj = 0; fj < 4; ++fj)
                    acc[fi][fj] = __builtin_amdgcn_mfma_f32_16x16x32_bf16(
                        af[fi], bv[fj], acc[fi][fj], 0, 0, 0);
        }
        __syncthreads();
    }

    // epilogue: D col = lane&15, row = (lane>>4)*4 + reg (verified round 1)
    const int mbase = m0 + wr * 64;
    const int cbase = g0 + wc * 64;
    #pragma unroll
    for (int fi = 0; fi < 4; ++fi) {
        float bvv[4];
        #pragma unroll
        for (int r = 0; r < 4; ++r)
            bvv[r] = bias[mbase + fi * 16 + lkh * 4 + r];
        #pragma unroll
        for (int fj = 0; fj < 4; ++fj) {
            const int gcol = cbase + fj * 16 + la;
            const int n2 = gcol / SPATIAL;
            const int p2 = gcol % SPATIAL;
            float* op = out + (size_t)(n2 * K_OUT) * SPATIAL + p2;
            #pragma unroll
            for (int r = 0; r < 4; ++r) {
                const int m = mbase + fi * 16 + lkh * 4 + r;
                op[(size_t)m * SPATIAL] = acc[fi][fj][r] + bvv[r];
            }
        }
    }
}

// ---------------- fallback (round-1 path) if ws is too small ----------------
#define LDK 40
__global__ __launch_bounds__(256)
void conv_mfma_fallback(const float* __restrict__ in,
                        const float* __restrict__ wraw,
                        const float* __restrict__ bias,
                        float* __restrict__ out) {
    __shared__ __attribute__((aligned(16))) unsigned short lA[BM * LDK];
    __shared__ __attribute__((aligned(16))) unsigned short lB[BN * LDK];
    const int tid = threadIdx.x;
    const int m0  = blockIdx.y * BM;
    const int g0  = blockIdx.x * BN;
    const int wave = tid >> 6, lane = tid & 63;
    const int wr = wave >> 1, wc = wave & 1;
    const int la = lane & 15, lkh = lane >> 4, lk = lkh * 8;

    f32x4 acc[4][4];
    #pragma unroll
    for (int i = 0; i < 4; ++i)
        #pragma unroll
        for (int j = 0; j < 4; ++j)
            acc[i][j] = (f32x4){0.f, 0.f, 0.f, 0.f};

    const int jj = tid & 127;
    const int kb = (tid >> 7) * 16;
    const int g = g0 + jj;
    const int nimg = g / SPATIAL;
    const int pos  = g % SPATIAL;
    const int oh = pos / HW, ow = pos % HW;

    for (int tap = 0; tap < 9; ++tap) {
        const int dr = tap / 3 - 1, ds = tap % 3 - 1;
        const int ih = oh + dr, iw = ow + ds;
        const bool valid = ((unsigned)ih < HW) && ((unsigned)iw < HW);
        const float* src = in + ((nimg * C_IN) * HW + ih) * HW + iw;
        for (int c0 = 0; c0 < C_IN; c0 += 32) {
            #pragma unroll
            for (int i = 0; i < 2; ++i) {
                const int ch = tid * 2 + i;
                const int row = ch >> 2;
                const int kp = (ch & 3) * 8;
                ushort8 v;
                #pragma unroll
                for (int e = 0; e < 8; ++e)
                    v[e] = f2bf(wraw[((m0 + row) * C_IN + c0 + kp + e) * 9 + tap]);
                *reinterpret_cast<ushort8*>(&lA[row * LDK + kp]) = v;
            }
            {
                ushort8 v0, v1;
                #pragma unroll
                for (int i = 0; i < 8; ++i)
                    v0[i] = f2bf(valid ? src[(c0 + kb + i) * SPATIAL] : 0.f);
                #pragma unroll
                for (int i = 0; i < 8; ++i)
                    v1[i] = f2bf(valid ? src[(c0 + kb + 8 + i) * SPATIAL] : 0.f);
                *reinterpret_cast<ushort8*>(&lB[jj * LDK + kb])     = v0;
                *reinterpret_cast<ushort8*>(&lB[jj * LDK + kb + 8]) = v1;
            }
            __syncthreads();
            bf16x8 af[4], bv[4];
            #pragma unroll
            for (int f = 0; f < 4; ++f) {
                af[f] = *reinterpret_cast<const bf16x8*>(&lA[(wr * 64 + f * 16 + la) * LDK + lk]);
                bv[f] = *reinterpret_cast<const bf16x8*>(&lB[(wc * 64 + f * 16 + la) * LDK + lk]);
            }
            #pragma unroll
            for (int fi = 0; fi < 4; ++fi)
                #pragma unroll
                for (int fj = 0; fj < 4; ++fj)
                    acc[fi][fj] = __builtin_amdgcn_mfma_f32_16x16x32_bf16(
                        af[fi], bv[fj], acc[fi][fj], 0, 0, 0);
            __syncthreads();
        }
    }
    const int mbase = m0 + wr * 64;
    const int cbase = g0 + wc * 64;
    #pragma unroll
    for (int fi = 0; fi < 4; ++fi) {
        float bvv[4];
        #pragma unroll
        for (int r = 0; r < 4; ++r)
            bvv[r] = bias[mbase + fi * 16 + lkh * 4 + r];
        #pragma unroll
        for (int fj = 0; fj < 4; ++fj) {
            const int gcol = cbase + fj * 16 + la;
            const int n2 = gcol / SPATIAL;
            const int p2 = gcol % SPATIAL;
            float* op = out + (size_t)(n2 * K_OUT) * SPATIAL + p2;
            #pragma unroll
            for (int r = 0; r < 4; ++r)
                op[(size_t)(mbase + fi * 16 + lkh * 4 + r) * SPATIAL] = acc[fi][fj][r] + bvv[r];
        }
    }
}

extern "C" void kernel_launch(void* const* d_in, const int* in_sizes, int n_in,
                              void* d_out, int out_size, void* d_ws, size_t ws_size,
                              hipStream_t stream) {
    const float* in   = (const float*)d_in[0];
    const float* w    = (const float*)d_in[1];
    const float* bias = (const float*)d_in[2];
    float* out = (float*)d_out;

    // ws layout (halves): w2 [294912] | nhwc [12845056] | zbuf [64]
    const size_t need_bytes = (294912ull + 12845056ull + 64ull) * 2ull;
    dim3 grid(GEMM_N / BN, K_OUT / BM);   // (784, 2)

    if (ws_size >= need_bytes) {
        unsigned short* w2   = (unsigned short*)d_ws;
        unsigned short* nhwc = w2 + 294912;
        unsigned short* zbuf = nhwc + 12845056;
        wtrans_kernel<<<(K_OUT * GEMM_K) / 256, 256, 0, stream>>>(w, w2);
        intrans_kernel<<<32 * HW, 256, 0, stream>>>(in, nhwc);
        hipMemsetAsync(zbuf, 0, 128, stream);
        conv_mfma_nhwc<<<grid, 256, 0, stream>>>(nhwc, w2, zbuf, bias, out);
    } else {
        conv_mfma_fallback<<<grid, 256, 0, stream>>>(in, w, bias, out);
    }
}

// Round 3
// 107.210 us; speedup vs baseline: 2.2200x; 1.2434x over previous
//
#include <hip/hip_runtime.h>
#include <hip/hip_bf16.h>
#include <stdint.h>

// DenseConv2d: input (32,128,56,56) f32, weight (256,128,3,3) f32, bias (256) f32
// stride 1, pad 1 -> out (32,256,56,56) f32.
// Implicit GEMM: C[256][100352] = W[256][1152] x im2col[1152][100352], bf16 MFMA.
// Round 3: 3-deep counted-vmcnt pipeline (T3+T4), BK=32 conflict-free linear LDS,
// 128x64 wave tiles, XCD swizzle (T1), setprio (T5).

typedef __attribute__((ext_vector_type(8))) short bf16x8;
typedef __attribute__((ext_vector_type(8))) unsigned short ushort8;
typedef __attribute__((ext_vector_type(4))) float f32x4;

#define HW      56
#define SPATIAL 3136        // 56*56
#define C_IN    128
#define K_OUT   256
#define GEMM_K  1152        // 9 * 128, ordered k = tap*128 + c
#define GEMM_N  100352      // 32 * 3136

#define BM 128
#define BN 256
#define BK 32
#define NT 36               // 9 taps * (128/32)
#define BUF_HALVES 12288    // lA 128*32 + lB 256*32
#define LB_OFF 4096         // lA halves per buffer

__device__ __forceinline__ unsigned short f2bf(float f) {
    union { float f; unsigned int u; } v; v.f = f;
    unsigned int u = v.u + 0x7FFFu + ((v.u >> 16) & 1u);   // RTNE
    return (unsigned short)(u >> 16);
}

__device__ __forceinline__ void gload16(const unsigned short* g, unsigned short* l) {
    __builtin_amdgcn_global_load_lds(
        (const __attribute__((address_space(1))) unsigned int*)(g),
        (__attribute__((address_space(3))) unsigned int*)(l),
        16, 0, 0);
}

// weight [256][128][3][3] f32 -> w2 [256][9][128] bf16  (k_out, tap, c)
__global__ void wtrans_kernel(const float* __restrict__ w, unsigned short* __restrict__ w2) {
    int idx = blockIdx.x * 256 + threadIdx.x;       // 294912 total
    int ko  = idx / GEMM_K;
    int r   = idx % GEMM_K;
    int tap = r >> 7;
    int c   = r & 127;
    w2[idx] = f2bf(w[(ko * C_IN + c) * 9 + tap]);
}

// input [32][128][56][56] f32 -> nhwc [32][56][56][128] bf16
__global__ __launch_bounds__(256)
void intrans_kernel(const float* __restrict__ in, unsigned short* __restrict__ nhwc) {
    __shared__ __attribute__((aligned(16))) unsigned short l[56 * 136];
    const int bx = blockIdx.x;                      // 32*56 = 1792
    const int n = bx / HW, h = bx % HW;
    const int tid = threadIdx.x;
    const float* src = in + (size_t)n * C_IN * SPATIAL + h * HW;
    #pragma unroll
    for (int i = 0; i < 28; ++i) {                  // 7168 = 28*256
        int idx = i * 256 + tid;
        int c = idx / HW, w = idx % HW;
        l[w * 136 + c] = f2bf(src[(size_t)c * SPATIAL + w]);
    }
    __syncthreads();
    unsigned short* dst = nhwc + ((size_t)(n * HW + h) * HW) * C_IN;
    #pragma unroll
    for (int j = 0; j < 4; ++j) {
        int chunk = j * 256 + tid;                  // 896 = 56*16 chunks of 8
        if (chunk < 896) {
            int w = chunk >> 4, c8 = chunk & 15;
            *reinterpret_cast<ushort8*>(dst + w * C_IN + c8 * 8) =
                *reinterpret_cast<const ushort8*>(&l[w * 136 + c8 * 8]);
        }
    }
}

// ---------------- main kernel: 3-deep counted-vmcnt pipeline ----------------
__global__ __launch_bounds__(256, 2)
void conv_mfma_pipe(const unsigned short* __restrict__ nhwc,
                    const unsigned short* __restrict__ w2,
                    const unsigned short* __restrict__ zbuf,
                    const float* __restrict__ bias,
                    float* __restrict__ out) {
    __shared__ __attribute__((aligned(16))) unsigned short lds[3 * BUF_HALVES]; // 72 KiB

    const int tid  = threadIdx.x;
    const int wave = tid >> 6;
    const int lane = tid & 63;
    const int la   = lane & 15;
    const int lkh  = lane >> 4;

    // bijective XCD swizzle: 784 blocks, 784 % 8 == 0
    const int bid = blockIdx.y * 392 + blockIdx.x;
    const int swz = (bid & 7) * 98 + (bid >> 3);
    const int m0  = (swz / 392) * BM;
    const int g0  = (swz % 392) * BN;

    // ---- per-lane staging descriptors ----
    // A: lane covers row rbase + (lane>>2), granule (lane&3)*8 halves
    const unsigned short* wsrc[2];
    #pragma unroll
    for (int ja = 0; ja < 2; ++ja)
        wsrc[ja] = w2 + (size_t)(m0 + ja * 64 + wave * 16 + (lane >> 2)) * GEMM_K
                      + (lane & 3) * 8;
    // B: 4 column groups of 64 (16 per wave per issue)
    int ohs[4], ows[4], pb[4];
    #pragma unroll
    for (int jb = 0; jb < 4; ++jb) {
        int col  = g0 + jb * 64 + wave * 16 + (lane >> 2);
        int nimg = col / SPATIAL;
        int pos  = col - nimg * SPATIAL;
        int oh   = pos / HW;
        int ow   = pos - oh * HW;
        ohs[jb] = oh; ows[jb] = ow;
        pb[jb]  = ((nimg * HW + oh) * HW + ow) * C_IN;
    }
    const int gq = (lane & 3) * 8;

    f32x4 acc[8][4];
    #pragma unroll
    for (int i = 0; i < 8; ++i)
        #pragma unroll
        for (int j = 0; j < 4; ++j)
            acc[i][j] = (f32x4){0.f, 0.f, 0.f, 0.f};

    auto STAGE = [&](int s, int bufi) {
        const int tap = s >> 2, ci = (s & 3) * 32;
        const int dr = tap / 3 - 1, dsx = tap % 3 - 1;
        unsigned short* bA = &lds[bufi * BUF_HALVES];
        unsigned short* bB = bA + LB_OFF;
        #pragma unroll
        for (int ja = 0; ja < 2; ++ja)
            gload16(wsrc[ja] + tap * C_IN + ci, bA + (ja * 64 + wave * 16) * BK);
        const int doff = (dr * HW + dsx) * C_IN + ci;
        #pragma unroll
        for (int jb = 0; jb < 4; ++jb) {
            const int ih = ohs[jb] + dr, iw = ows[jb] + dsx;
            const bool valid = ((unsigned)ih < HW) && ((unsigned)iw < HW);
            const unsigned short* src = valid ? nhwc + pb[jb] + doff + gq
                                              : zbuf + gq;
            gload16(src, bB + (jb * 64 + wave * 16) * BK);
        }
    };

    // prologue: 3 stages in flight (18 loads)
    STAGE(0, 0); STAGE(1, 1); STAGE(2, 2);

    int cur = 0;
    for (int t = 0; t < NT; ++t) {
        // wait for stage t (6 loads per stage; keep 2 newer stages in flight)
        if (t <= NT - 3)      asm volatile("s_waitcnt vmcnt(12)" ::: "memory");
        else if (t == NT - 2) asm volatile("s_waitcnt vmcnt(6)"  ::: "memory");
        else                  asm volatile("s_waitcnt vmcnt(0)"  ::: "memory");
        __builtin_amdgcn_s_barrier();
        asm volatile("" ::: "memory");

        const unsigned short* A = &lds[cur * BUF_HALVES];
        const unsigned short* B = A + LB_OFF;
        bf16x8 af[8], bv[4];
        #pragma unroll
        for (int mi = 0; mi < 8; ++mi)
            af[mi] = *reinterpret_cast<const bf16x8*>(&A[(mi * 16 + la) * BK + lkh * 8]);
        #pragma unroll
        for (int nj = 0; nj < 4; ++nj)
            bv[nj] = *reinterpret_cast<const bf16x8*>(&B[(wave * 64 + nj * 16 + la) * BK + lkh * 8]);

        __builtin_amdgcn_s_setprio(1);
        #pragma unroll
        for (int mi = 0; mi < 8; ++mi)
            #pragma unroll
            for (int nj = 0; nj < 4; ++nj)
                acc[mi][nj] = __builtin_amdgcn_mfma_f32_16x16x32_bf16(
                    af[mi], bv[nj], acc[mi][nj], 0, 0, 0);
        __builtin_amdgcn_s_setprio(0);

        asm volatile("s_waitcnt lgkmcnt(0)" ::: "memory");
        __builtin_amdgcn_s_barrier();
        asm volatile("" ::: "memory");

        if (t < NT - 3) STAGE(t + 3, cur);
        cur = (cur == 2) ? 0 : cur + 1;
    }

    // ---- epilogue: D col = lane&15, row = (lane>>4)*4 + reg ----
    #pragma unroll
    for (int mi = 0; mi < 8; ++mi) {
        const f32x4 bv4 = *reinterpret_cast<const f32x4*>(&bias[m0 + mi * 16 + lkh * 4]);
        #pragma unroll
        for (int nj = 0; nj < 4; ++nj) {
            const int gcol = g0 + wave * 64 + nj * 16;       // 16-aligned, no image straddle
            const int n2 = gcol / SPATIAL;
            const int p2 = gcol - n2 * SPATIAL + la;
            float* op = out + ((size_t)(n2 * K_OUT + m0 + mi * 16 + lkh * 4)) * SPATIAL + p2;
            op[0]               = acc[mi][nj][0] + bv4[0];
            op[SPATIAL]         = acc[mi][nj][1] + bv4[1];
            op[2 * SPATIAL]     = acc[mi][nj][2] + bv4[2];
            op[3 * (size_t)SPATIAL] = acc[mi][nj][3] + bv4[3];
        }
    }
}

// ---------------- fallback (round-1 path) if ws is too small ----------------
#define LDK 40
__global__ __launch_bounds__(256)
void conv_mfma_fallback(const float* __restrict__ in,
                        const float* __restrict__ wraw,
                        const float* __restrict__ bias,
                        float* __restrict__ out) {
    __shared__ __attribute__((aligned(16))) unsigned short lA[BM * LDK];
    __shared__ __attribute__((aligned(16))) unsigned short lB[128 * LDK];
    const int tid = threadIdx.x;
    const int m0  = blockIdx.y * BM;
    const int g0  = blockIdx.x * 128;
    const int wave = tid >> 6, lane = tid & 63;
    const int wr = wave >> 1, wc = wave & 1;
    const int la = lane & 15, lkh = lane >> 4, lk = lkh * 8;

    f32x4 acc[4][4];
    #pragma unroll
    for (int i = 0; i < 4; ++i)
        #pragma unroll
        for (int j = 0; j < 4; ++j)
            acc[i][j] = (f32x4){0.f, 0.f, 0.f, 0.f};

    const int jj = tid & 127;
    const int kb = (tid >> 7) * 16;
    const int g = g0 + jj;
    const int nimg = g / SPATIAL;
    const int pos  = g % SPATIAL;
    const int oh = pos / HW, ow = pos % HW;

    for (int tap = 0; tap < 9; ++tap) {
        const int dr = tap / 3 - 1, dsx = tap % 3 - 1;
        const int ih = oh + dr, iw = ow + dsx;
        const bool valid = ((unsigned)ih < HW) && ((unsigned)iw < HW);
        const float* src = in + ((nimg * C_IN) * HW + ih) * HW + iw;
        for (int c0 = 0; c0 < C_IN; c0 += 32) {
            #pragma unroll
            for (int i = 0; i < 2; ++i) {
                const int ch = tid * 2 + i;
                const int row = ch >> 2;
                const int kp = (ch & 3) * 8;
                ushort8 v;
                #pragma unroll
                for (int e = 0; e < 8; ++e)
                    v[e] = f2bf(wraw[((m0 + row) * C_IN + c0 + kp + e) * 9 + tap]);
                *reinterpret_cast<ushort8*>(&lA[row * LDK + kp]) = v;
            }
            {
                ushort8 v0, v1;
                #pragma unroll
                for (int i = 0; i < 8; ++i)
                    v0[i] = f2bf(valid ? src[(c0 + kb + i) * SPATIAL] : 0.f);
                #pragma unroll
                for (int i = 0; i < 8; ++i)
                    v1[i] = f2bf(valid ? src[(c0 + kb + 8 + i) * SPATIAL] : 0.f);
                *reinterpret_cast<ushort8*>(&lB[jj * LDK + kb])     = v0;
                *reinterpret_cast<ushort8*>(&lB[jj * LDK + kb + 8]) = v1;
            }
            __syncthreads();
            bf16x8 af[4], bv[4];
            #pragma unroll
            for (int f = 0; f < 4; ++f) {
                af[f] = *reinterpret_cast<const bf16x8*>(&lA[(wr * 64 + f * 16 + la) * LDK + lk]);
                bv[f] = *reinterpret_cast<const bf16x8*>(&lB[(wc * 64 + f * 16 + la) * LDK + lk]);
            }
            #pragma unroll
            for (int fi = 0; fi < 4; ++fi)
                #pragma unroll
                for (int fj = 0; fj < 4; ++fj)
                    acc[fi][fj] = __builtin_amdgcn_mfma_f32_16x16x32_bf16(
                        af[fi], bv[fj], acc[fi][fj], 0, 0, 0);
            __syncthreads();
        }
    }
    const int mbase = m0 + wr * 64;
    const int cbase = g0 + wc * 64;
    #pragma unroll
    for (int fi = 0; fi < 4; ++fi) {
        float bvv[4];
        #pragma unroll
        for (int r = 0; r < 4; ++r)
            bvv[r] = bias[mbase + fi * 16 + lkh * 4 + r];
        #pragma unroll
        for (int fj = 0; fj < 4; ++fj) {
            const int gcol = cbase + fj * 16 + la;
            const int n2 = gcol / SPATIAL;
            const int p2 = gcol % SPATIAL;
            float* op = out + (size_t)(n2 * K_OUT) * SPATIAL + p2;
            #pragma unroll
            for (int r = 0; r < 4; ++r)
                op[(size_t)(mbase + fi * 16 + lkh * 4 + r) * SPATIAL] = acc[fi][fj][r] + bvv[r];
        }
    }
}

extern "C" void kernel_launch(void* const* d_in, const int* in_sizes, int n_in,
                              void* d_out, int out_size, void* d_ws, size_t ws_size,
                              hipStream_t stream) {
    const float* in   = (const float*)d_in[0];
    const float* w    = (const float*)d_in[1];
    const float* bias = (const float*)d_in[2];
    float* out = (float*)d_out;

    // ws layout (halves): w2 [294912] | nhwc [12845056] | zbuf [64]
    const size_t need_bytes = (294912ull + 12845056ull + 64ull) * 2ull;

    if (ws_size >= need_bytes) {
        unsigned short* w2   = (unsigned short*)d_ws;
        unsigned short* nhwc = w2 + 294912;
        unsigned short* zbuf = nhwc + 12845056;
        wtrans_kernel<<<(K_OUT * GEMM_K) / 256, 256, 0, stream>>>(w, w2);
        intrans_kernel<<<32 * HW, 256, 0, stream>>>(in, nhwc);
        hipMemsetAsync(zbuf, 0, 128, stream);
        dim3 grid(GEMM_N / BN, K_OUT / BM);   // (392, 2) = 784 blocks
        conv_mfma_pipe<<<grid, 256, 0, stream>>>(nhwc, w2, zbuf, bias, out);
    } else {
        dim3 grid(GEMM_N / 128, K_OUT / BM);
        conv_mfma_fallback<<<grid, 256, 0, stream>>>(in, w, bias, out);
    }
}